// Round 2
// baseline (2799.738 us; speedup 1.0000x reference)
//
#include <hip/hip_runtime.h>
#include <math.h>

// Problem constants
#define TSEQ   1024
#define DMODEL 256
#define NHEAD  8
#define DHEAD  32
#define NREL   2047
#define OUT0   2097152   // B*T*D elements (output 0 size)

// workspace layout (float offsets; ws total = 9,436,672 floats = 37.75 MB)
//  0        : qbuf fp32                     [8][8][1024][32]   8 MB
//  2097152  : khi/klo bf16                  [8][8][1024][32]x2 8 MB
//  4194304  : vthi/vtlo bf16 (transposed)   [8][8][32][1024]x2 8 MB
//  6291456  : phi/plo bf16                  [8][2047][32]x2    2 MB
//  6815488  : O region 8 MB = xhi/xlo (prep..proj) then obhi/oblo (attn..oproj)
//  8912640  : wsplit: 5 matrices x (hi 65536 + lo 65536) ushort = 1.25 MB

typedef __attribute__((ext_vector_type(8))) short bf16x8;   // 8 bf16 = 4 VGPRs
typedef __attribute__((ext_vector_type(4))) float f32x4;    // MFMA accumulator

#define MFMA16 __builtin_amdgcn_mfma_f32_16x16x32_bf16

// split fp32 x into bf16 hi + bf16 lo (x ~= hi + lo, dropped part ~2^-18*x)
__device__ __forceinline__ void split2(float x, unsigned short& h, unsigned short& l) {
  unsigned u = __float_as_uint(x);
  unsigned r = (u + 0x7fffu + ((u >> 16) & 1u)) >> 16;   // RNE to bf16
  h = (unsigned short)r;
  float res = x - __uint_as_float(r << 16);
  unsigned u2 = __float_as_uint(res);
  l = (unsigned short)((u2 + 0x7fffu + ((u2 >> 16) & 1u)) >> 16);
}

__device__ __forceinline__ void cvt8(const float* x, bf16x8& h8, bf16x8& l8) {
#pragma unroll
  for (int e = 0; e < 8; ++e) {
    unsigned short a, b;
    split2(x[e], a, b);
    h8[e] = (short)a;
    l8[e] = (short)b;
  }
}

// ---------------------------------------------------------------------------
// One-shot elementwise split: X -> xhi/xlo; Wq,Wk,Wv,Wp,Wo -> wsplit.
__global__ __launch_bounds__(256) void split_kernel(
    const float* __restrict__ X, const float* __restrict__ Wq,
    const float* __restrict__ Wk, const float* __restrict__ Wv,
    const float* __restrict__ Wp, const float* __restrict__ Wo,
    unsigned short* __restrict__ xhi, unsigned short* __restrict__ xlo,
    unsigned short* __restrict__ wsp)
{
  const int idx = blockIdx.x * 256 + threadIdx.x;   // one float4 each
  const float* src;
  unsigned short *dh, *dl;
  int e;
  if (idx < 524288) {               // X: 2,097,152 floats
    src = X; e = idx; dh = xhi; dl = xlo;
  } else {                          // W: 5 x 65536 floats
    const int j = idx - 524288;
    const int m = j >> 14;          // 16384 float4 per matrix
    e = j & 16383;
    src = m == 0 ? Wq : m == 1 ? Wk : m == 2 ? Wv : m == 3 ? Wp : Wo;
    dh = wsp + m * 131072;
    dl = dh + 65536;
  }
  const float4 v = ((const float4*)src)[e];
  unsigned short h0, l0, h1, l1, h2, l2, h3, l3;
  split2(v.x, h0, l0); split2(v.y, h1, l1);
  split2(v.z, h2, l2); split2(v.w, h3, l3);
  ((ushort4*)dh)[e] = make_ushort4(h0, h1, h2, h3);
  ((ushort4*)dl)[e] = make_ushort4(l0, l1, l2, l3);
}

// ---------------------------------------------------------------------------
// MFMA QKV projection. No LDS, no barriers: A (X-split) and B (W-split) frags
// are contiguous bf16x8 global loads. Block = 64 rows x 128 cols, 4 waves
// (wave w -> rows 16w..16w+15, 8 col-tiles). grid (128, 6): y>>1 = sel.
// Q written fp32 [bh][t][d]; K split [bh][t][d]; V split TRANSPOSED [bh][d][t].
__global__ __launch_bounds__(256) void proj_qkv_mfma(
    const unsigned short* __restrict__ xhi, const unsigned short* __restrict__ xlo,
    const unsigned short* __restrict__ wsp,
    const float* __restrict__ bq, const float* __restrict__ bk, const float* __restrict__ bv,
    float* __restrict__ qbuf,
    unsigned short* __restrict__ khi, unsigned short* __restrict__ klo,
    unsigned short* __restrict__ vthi, unsigned short* __restrict__ vtlo)
{
  const int sel = blockIdx.y >> 1;
  const int c0  = (blockIdx.y & 1) * 128;
  const int bt0 = blockIdx.x * 64;
  const int tid = threadIdx.x;
  const int w = tid >> 6, lane = tid & 63, lc = lane & 15, lg = lane >> 4;
  const unsigned short* wh = wsp + sel * 131072;
  const unsigned short* wl = wh + 65536;
  const float* bia = sel == 0 ? bq : (sel == 1 ? bk : bv);

  const int arow = bt0 + 16 * w + lc;
  bf16x8 ah[8], al[8];
#pragma unroll
  for (int ks = 0; ks < 8; ++ks) {
    const size_t o = (size_t)arow * 256 + ks * 32 + 8 * lg;
    ah[ks] = *(const bf16x8*)&xhi[o];
    al[ks] = *(const bf16x8*)&xlo[o];
  }
  const f32x4 zf = {0.f, 0.f, 0.f, 0.f};
  for (int ct = 0; ct < 8; ++ct) {
    const int n = c0 + ct * 16 + lc;
    f32x4 acc = zf;
#pragma unroll
    for (int ks = 0; ks < 8; ++ks) {
      const size_t o = (size_t)n * 256 + ks * 32 + 8 * lg;
      const bf16x8 bh8 = *(const bf16x8*)&wh[o];
      const bf16x8 bl8 = *(const bf16x8*)&wl[o];
      acc = MFMA16(ah[ks], bh8, acc, 0, 0, 0);
      acc = MFMA16(al[ks], bh8, acc, 0, 0, 0);
      acc = MFMA16(ah[ks], bl8, acc, 0, 0, 0);
    }
    const float bz = bia[n];
    const int hh = n >> 5, dd = n & 31;
#pragma unroll
    for (int r = 0; r < 4; ++r) {
      const int bt = bt0 + 16 * w + 4 * lg + r;
      const int bb = bt >> 10, t = bt & 1023;
      const float val = acc[r] + bz;
      if (sel == 0) {
        qbuf[(((size_t)bb * NHEAD + hh) * TSEQ + t) * DHEAD + dd] = val;
      } else if (sel == 1) {
        unsigned short a2, b2; split2(val, a2, b2);
        const size_t o2 = (((size_t)bb * NHEAD + hh) * TSEQ + t) * DHEAD + dd;
        khi[o2] = a2; klo[o2] = b2;
      } else {
        unsigned short a2, b2; split2(val, a2, b2);
        const size_t o2 = (((size_t)bb * NHEAD + hh) * DHEAD + dd) * TSEQ + t;
        vthi[o2] = a2; vtlo[o2] = b2;
      }
    }
  }
}

// ---------------------------------------------------------------------------
// MFMA P projection with on-the-fly sinusoidal PE generation (A frags computed
// in registers: sin/cos + split, once per block). grid (32, 2).
__global__ __launch_bounds__(256) void pgemm_mfma(
    const unsigned short* __restrict__ wph,
    unsigned short* __restrict__ phi, unsigned short* __restrict__ plo)
{
  const unsigned short* wpl = wph + 65536;
  const int bt0 = blockIdx.x * 64;
  const int c0  = blockIdx.y * 128;
  const int tid = threadIdx.x;
  const int w = tid >> 6, lane = tid & 63, lc = lane & 15, lg = lane >> 4;

  const int prow = bt0 + 16 * w + lc;
  const float rr_ = (float)(prow - 1023);
  bf16x8 ah[8], al[8];
#pragma unroll
  for (int ks = 0; ks < 8; ++ks) {
    const int cb2 = (32 * ks + 8 * lg) >> 1;   // m index base (col/2)
#pragma unroll
    for (int p = 0; p < 4; ++p) {
      // denom = 10000^(-m/128) = 2^(-m*log2(1e4)/128)
      const float denom = exp2f((float)(cb2 + p) * -0.10381025296523007f);
      const float ang = rr_ * denom;
      unsigned short hx, lx;
      split2(sinf(ang), hx, lx); ah[ks][2 * p]     = (short)hx; al[ks][2 * p]     = (short)lx;
      split2(cosf(ang), hx, lx); ah[ks][2 * p + 1] = (short)hx; al[ks][2 * p + 1] = (short)lx;
    }
  }
  const f32x4 zf = {0.f, 0.f, 0.f, 0.f};
  for (int ct = 0; ct < 8; ++ct) {
    const int n = c0 + ct * 16 + lc;
    f32x4 acc = zf;
#pragma unroll
    for (int ks = 0; ks < 8; ++ks) {
      const size_t o = (size_t)n * 256 + ks * 32 + 8 * lg;
      const bf16x8 bh8 = *(const bf16x8*)&wph[o];
      const bf16x8 bl8 = *(const bf16x8*)&wpl[o];
      acc = MFMA16(ah[ks], bh8, acc, 0, 0, 0);
      acc = MFMA16(al[ks], bh8, acc, 0, 0, 0);
      acc = MFMA16(ah[ks], bl8, acc, 0, 0, 0);
    }
    const int hh = n >> 5, dd = n & 31;
#pragma unroll
    for (int r = 0; r < 4; ++r) {
      const int rr2 = bt0 + 16 * w + 4 * lg + r;
      if (rr2 < NREL) {
        unsigned short a2, b2;
        split2(acc[r], a2, b2);
        const size_t o2 = ((size_t)hh * NREL + rr2) * DHEAD + dd;
        phi[o2] = a2; plo[o2] = b2;
      }
    }
  }
}

// ---------------------------------------------------------------------------
// MFMA attention. One block = (b,h, 64-row i-tile); 4 waves; LDS 51.2 KB ->
// 3 blocks/CU. V read as pre-split transposed bf16 straight from global (no
// LDS staging, no in-loop V conversion). obuf written pre-split bf16 hi/lo.
__global__ __launch_bounds__(256, 3) void attn_kernel(
    const float* __restrict__ qbuf,
    const unsigned short* __restrict__ khi, const unsigned short* __restrict__ klo,
    const unsigned short* __restrict__ vthi, const unsigned short* __restrict__ vtlo,
    const unsigned short* __restrict__ phi, const unsigned short* __restrict__ plo,
    const float* __restrict__ ub, const float* __restrict__ vbias,
    float* __restrict__ attn_out,
    unsigned short* __restrict__ obhi, unsigned short* __restrict__ oblo)
{
  __shared__ float smem[12800];          // 51.2 KB
  float* const Mlds = smem;              // [64][132] M chunk
  float* const Pt   = smem + 8448;       // [64][68]  probs tile

  const int orig = blockIdx.x;
  const int blk  = (orig & 7) * 128 + (orig >> 3);   // XCD swizzle (1024 % 8 == 0)
  const int bh   = blk >> 4;
  const int i0   = (blk & 15) << 6;
  const int h    = bh & 7;
  const int bb   = bh >> 3;
  const int tid  = threadIdx.x;
  const int w    = tid >> 6;             // wave 0..3
  const int lane = tid & 63;
  const int lc   = lane & 15;            // A row / B col within 16-subtile
  const int lg   = lane >> 4;            // k-group (8 elems each)

  const float* __restrict__ qrow = qbuf + (size_t)bh * (TSEQ * DHEAD);
  const unsigned short* __restrict__ kh = khi + (size_t)bh * (TSEQ * DHEAD);
  const unsigned short* __restrict__ kl = klo + (size_t)bh * (TSEQ * DHEAD);
  const unsigned short* __restrict__ vth = vthi + (size_t)bh * (DHEAD * TSEQ);
  const unsigned short* __restrict__ vtl = vtlo + (size_t)bh * (DHEAD * TSEQ);
  const unsigned short* __restrict__ ph_ = phi + (size_t)h * ((size_t)NREL * DHEAD);
  const unsigned short* __restrict__ pl_ = plo + (size_t)h * ((size_t)NREL * DHEAD);
  float* __restrict__ arow = attn_out + (size_t)bh * ((size_t)TSEQ * TSEQ);

  // ---- prologue: build qu/qv A-fragments (row = lc, k = 8*lg + e) ----
  bf16x8 quh, qul, qvh, qvl;
  {
    float q8[8];
    const float* qp = &qrow[(size_t)(i0 + 16 * w + lc) * DHEAD + 8 * lg];
    *(float4*)&q8[0] = *(const float4*)&qp[0];
    *(float4*)&q8[4] = *(const float4*)&qp[4];
#pragma unroll
    for (int e = 0; e < 8; ++e) {
      const float uu = ub[h * DHEAD + 8 * lg + e];
      const float vv = vbias[h * DHEAD + 8 * lg + e];
      unsigned short a, b;
      split2(q8[e] + uu, a, b); quh[e] = (short)a; qul[e] = (short)b;
      split2(q8[e] + vv, a, b); qvh[e] = (short)a; qvl[e] = (short)b;
    }
  }

  const float KSC = 0.09016844136f;      // 1/(sqrt(256)*ln2)
  float m_l[4], sm_l[4];
#pragma unroll
  for (int r = 0; r < 4; ++r) { m_l[r] = -1e30f; sm_l[r] = 0.f; }

  const f32x4 zf = {0.f, 0.f, 0.f, 0.f};

  // ================= sweep 1: stats =================
  for (int t = 0; t < 16; ++t) {
    const int j0 = t * 64;
    const int r0 = i0 - j0 + 960;        // first P row of this tile's M chunk
    f32x4 mf[8];
#pragma unroll
    for (int st = 0; st < 8; ++st) mf[st] = zf;
#pragma unroll
    for (int st = 0; st < 8; ++st) {
      int pr = r0 + 16 * st + lc;
      if (pr > 2046) pr = 2046;
      const size_t o = (size_t)pr * DHEAD + 8 * lg;
      const bf16x8 bh8 = *(const bf16x8*)&ph_[o];
      const bf16x8 bl8 = *(const bf16x8*)&pl_[o];
      mf[st] = MFMA16(qvh, bh8, mf[st], 0, 0, 0);
      mf[st] = MFMA16(qvl, bh8, mf[st], 0, 0, 0);
      mf[st] = MFMA16(qvh, bl8, mf[st], 0, 0, 0);
    }
    __syncthreads();                     // prev-tile gather finished
#pragma unroll
    for (int st = 0; st < 8; ++st)
#pragma unroll
      for (int r = 0; r < 4; ++r)
        Mlds[(16 * w + 4 * lg + r) * 132 + 16 * st + lc] = mf[st][r];

    f32x4 sf[4];
#pragma unroll
    for (int st = 0; st < 4; ++st) sf[st] = zf;
#pragma unroll
    for (int st = 0; st < 4; ++st) {
      const size_t o = (size_t)(j0 + 16 * st + lc) * DHEAD + 8 * lg;
      const bf16x8 bh8 = *(const bf16x8*)&kh[o];
      const bf16x8 bl8 = *(const bf16x8*)&kl[o];
      sf[st] = MFMA16(quh, bh8, sf[st], 0, 0, 0);
      sf[st] = MFMA16(qul, bh8, sf[st], 0, 0, 0);
      sf[st] = MFMA16(quh, bl8, sf[st], 0, 0, 0);
    }
    __syncthreads();                     // M chunk visible
#pragma unroll
    for (int st = 0; st < 4; ++st) {
      const int jloc = 16 * st + lc;
#pragma unroll
      for (int r = 0; r < 4; ++r) {
        const int il = 16 * w + 4 * lg + r;
        sf[st][r] += Mlds[il * 132 + (il - jloc + 63)];
      }
    }
#pragma unroll
    for (int r = 0; r < 4; ++r) {
      const float t0 = fmaxf(fmaxf(sf[0][r], sf[1][r]), fmaxf(sf[2][r], sf[3][r]));
      const float mn = fmaxf(m_l[r], t0);
      const float ps = exp2f((sf[0][r] - mn) * KSC) + exp2f((sf[1][r] - mn) * KSC)
                     + exp2f((sf[2][r] - mn) * KSC) + exp2f((sf[3][r] - mn) * KSC);
      sm_l[r] = sm_l[r] * exp2f((m_l[r] - mn) * KSC) + ps;
      m_l[r] = mn;
    }
  }

  // merge stats across the 16-lane row group
  float m_f[4], rs[4];
#pragma unroll
  for (int r = 0; r < 4; ++r) {
    float mm = m_l[r], ss = sm_l[r];
#pragma unroll
    for (int d = 1; d < 16; d <<= 1) {
      const float om = __shfl_xor(mm, d);
      const float os = __shfl_xor(ss, d);
      const float M2 = fmaxf(mm, om);
      ss = ss * exp2f((mm - M2) * KSC) + os * exp2f((om - M2) * KSC);
      mm = M2;
    }
    m_f[r] = mm;
    rs[r] = 1.0f / ss;
  }

  // ================= sweep 2: probs + AV =================
  f32x4 of0 = zf, of1 = zf;
  for (int t = 0; t < 16; ++t) {
    const int j0 = t * 64;
    const int r0 = i0 - j0 + 960;

    f32x4 mf[8];
#pragma unroll
    for (int st = 0; st < 8; ++st) mf[st] = zf;
#pragma unroll
    for (int st = 0; st < 8; ++st) {
      int pr = r0 + 16 * st + lc;
      if (pr > 2046) pr = 2046;
      const size_t o = (size_t)pr * DHEAD + 8 * lg;
      const bf16x8 bh8 = *(const bf16x8*)&ph_[o];
      const bf16x8 bl8 = *(const bf16x8*)&pl_[o];
      mf[st] = MFMA16(qvh, bh8, mf[st], 0, 0, 0);
      mf[st] = MFMA16(qvl, bh8, mf[st], 0, 0, 0);
      mf[st] = MFMA16(qvh, bl8, mf[st], 0, 0, 0);
    }
    __syncthreads();                     // A: prev tile's Pt reads done
#pragma unroll
    for (int st = 0; st < 8; ++st)
#pragma unroll
      for (int r = 0; r < 4; ++r)
        Mlds[(16 * w + 4 * lg + r) * 132 + 16 * st + lc] = mf[st][r];

    f32x4 sf[4];
#pragma unroll
    for (int st = 0; st < 4; ++st) sf[st] = zf;
#pragma unroll
    for (int st = 0; st < 4; ++st) {
      const size_t o = (size_t)(j0 + 16 * st + lc) * DHEAD + 8 * lg;
      const bf16x8 bh8 = *(const bf16x8*)&kh[o];
      const bf16x8 bl8 = *(const bf16x8*)&kl[o];
      sf[st] = MFMA16(quh, bh8, sf[st], 0, 0, 0);
      sf[st] = MFMA16(qul, bh8, sf[st], 0, 0, 0);
      sf[st] = MFMA16(quh, bl8, sf[st], 0, 0, 0);
    }
    __syncthreads();                     // B: M chunk visible

    // preload vT B-frags (L2) — latency hides under gather/exp phase
    const size_t vo0 = (size_t)lc * TSEQ + j0 + 8 * lg;         // d = lc
    const size_t vo1 = (size_t)(lc + 16) * TSEQ + j0 + 8 * lg;  // d = lc+16
    const bf16x8 v00h = *(const bf16x8*)&vth[vo0];
    const bf16x8 v00l = *(const bf16x8*)&vtl[vo0];
    const bf16x8 v01h = *(const bf16x8*)&vth[vo1];
    const bf16x8 v01l = *(const bf16x8*)&vtl[vo1];
    const bf16x8 v10h = *(const bf16x8*)&vth[vo0 + 32];
    const bf16x8 v10l = *(const bf16x8*)&vtl[vo0 + 32];
    const bf16x8 v11h = *(const bf16x8*)&vth[vo1 + 32];
    const bf16x8 v11l = *(const bf16x8*)&vtl[vo1 + 32];

#pragma unroll
    for (int st = 0; st < 4; ++st) {
      const int jloc = 16 * st + lc;
#pragma unroll
      for (int r = 0; r < 4; ++r) {
        const int il = 16 * w + 4 * lg + r;
        const float sv = sf[st][r] + Mlds[il * 132 + (il - jloc + 63)];
        const float p = exp2f((sv - m_f[r]) * KSC) * rs[r];
        Pt[il * 68 + jloc] = p;
      }
    }
    __syncthreads();                     // C: probs tile complete
    // global attn store (256B runs per row quarter)
    {
      const int prow = tid >> 2, cb = (tid & 3) * 16;
      float* gp = &arow[(size_t)(i0 + prow) * TSEQ + j0 + cb];
      const float* sp = &Pt[prow * 68 + cb];
#pragma unroll
      for (int qq = 0; qq < 4; ++qq)
        *(float4*)&gp[qq * 4] = *(const float4*)&sp[qq * 4];
    }
    // AV: O[16x32] += probs(16x64) x V(64x32); V frags already in registers
#pragma unroll
    for (int kc = 0; kc < 2; ++kc) {
      float tmp[8];
      const float* ap = &Pt[(16 * w + lc) * 68 + 32 * kc + 8 * lg];
      *(float4*)&tmp[0] = *(const float4*)&ap[0];
      *(float4*)&tmp[4] = *(const float4*)&ap[4];
      bf16x8 pah, pal;
      cvt8(tmp, pah, pal);
      const bf16x8 b0h = kc ? v10h : v00h;
      const bf16x8 b0l = kc ? v10l : v00l;
      const bf16x8 b1h = kc ? v11h : v01h;
      const bf16x8 b1l = kc ? v11l : v01l;
      of0 = MFMA16(pah, b0h, of0, 0, 0, 0);
      of0 = MFMA16(pal, b0h, of0, 0, 0, 0);
      of0 = MFMA16(pah, b0l, of0, 0, 0, 0);
      of1 = MFMA16(pah, b1h, of1, 0, 0, 0);
      of1 = MFMA16(pal, b1h, of1, 0, 0, 0);
      of1 = MFMA16(pah, b1l, of1, 0, 0, 0);
    }
  }

  // write O head slice pre-split for MFMA oproj
#pragma unroll
  for (int r = 0; r < 4; ++r) {
    const int row = i0 + 16 * w + 4 * lg + r;
    const size_t base = ((size_t)bb * TSEQ + row) * DMODEL + h * DHEAD;
    unsigned short a2, b2;
    split2(of0[r], a2, b2); obhi[base + lc]      = a2; oblo[base + lc]      = b2;
    split2(of1[r], a2, b2); obhi[base + lc + 16] = a2; oblo[base + lc + 16] = b2;
  }
}

// ---------------------------------------------------------------------------
// MFMA output projection: obuf-split x Wo-split + bo -> out0 fp32.
__global__ __launch_bounds__(256) void oproj_mfma(
    const unsigned short* __restrict__ obhi, const unsigned short* __restrict__ oblo,
    const unsigned short* __restrict__ woh,
    const float* __restrict__ bo, float* __restrict__ out)
{
  const unsigned short* wol = woh + 65536;
  const int c0  = blockIdx.y * 128;
  const int bt0 = blockIdx.x * 64;
  const int tid = threadIdx.x;
  const int w = tid >> 6, lane = tid & 63, lc = lane & 15, lg = lane >> 4;

  const int arow = bt0 + 16 * w + lc;
  bf16x8 ah[8], al[8];
#pragma unroll
  for (int ks = 0; ks < 8; ++ks) {
    const size_t o = (size_t)arow * 256 + ks * 32 + 8 * lg;
    ah[ks] = *(const bf16x8*)&obhi[o];
    al[ks] = *(const bf16x8*)&oblo[o];
  }
  const f32x4 zf = {0.f, 0.f, 0.f, 0.f};
  for (int ct = 0; ct < 8; ++ct) {
    const int n = c0 + ct * 16 + lc;
    f32x4 acc = zf;
#pragma unroll
    for (int ks = 0; ks < 8; ++ks) {
      const size_t o = (size_t)n * 256 + ks * 32 + 8 * lg;
      const bf16x8 bh8 = *(const bf16x8*)&woh[o];
      const bf16x8 bl8 = *(const bf16x8*)&wol[o];
      acc = MFMA16(ah[ks], bh8, acc, 0, 0, 0);
      acc = MFMA16(al[ks], bh8, acc, 0, 0, 0);
      acc = MFMA16(ah[ks], bl8, acc, 0, 0, 0);
    }
    const float bz = bo[n];
#pragma unroll
    for (int r = 0; r < 4; ++r) {
      const int bt = bt0 + 16 * w + 4 * lg + r;
      out[(size_t)bt * DMODEL + n] = acc[r] + bz;
    }
  }
}

// ---------------------------------------------------------------------------
extern "C" void kernel_launch(void* const* d_in, const int* in_sizes, int n_in,
                              void* d_out, int out_size, void* d_ws, size_t ws_size,
                              hipStream_t stream) {
  const float* X   = (const float*)d_in[0];
  const float* Wq  = (const float*)d_in[1];
  const float* bq  = (const float*)d_in[2];
  const float* Wk  = (const float*)d_in[3];
  const float* bk  = (const float*)d_in[4];
  const float* Wv  = (const float*)d_in[5];
  const float* bv  = (const float*)d_in[6];
  const float* Wp  = (const float*)d_in[7];
  const float* Wo  = (const float*)d_in[8];
  const float* bo  = (const float*)d_in[9];
  const float* ub  = (const float*)d_in[10];
  const float* vbb = (const float*)d_in[11];

  float* ws = (float*)d_ws;
  float* qbuf = ws;                                          // fp32 Q
  unsigned short* khi  = (unsigned short*)(ws + 2097152u);
  unsigned short* klo  = khi + 2097152u;
  unsigned short* vthi = (unsigned short*)(ws + 4194304u);
  unsigned short* vtlo = vthi + 2097152u;
  unsigned short* phi  = (unsigned short*)(ws + 6291456u);
  unsigned short* plo  = phi + 524032u;
  unsigned short* obhi = (unsigned short*)(ws + 6815488u);   // O region
  unsigned short* oblo = obhi + 2097152u;
  unsigned short* xhi  = obhi;   // alias: X-split dead before attn writes obuf
  unsigned short* xlo  = oblo;
  unsigned short* wsp  = (unsigned short*)(ws + 8912640u);   // 5x(hi+lo) W split

  float* out0 = (float*)d_out;
  float* attn = out0 + OUT0;

  split_kernel<<<2368, 256, 0, stream>>>(X, Wq, Wk, Wv, Wp, Wo, xhi, xlo, wsp);
  proj_qkv_mfma<<<dim3(128, 6), 256, 0, stream>>>(xhi, xlo, wsp, bq, bk, bv,
                                                  qbuf, khi, klo, vthi, vtlo);
  pgemm_mfma<<<dim3(32, 2), 256, 0, stream>>>(wsp + 3 * 131072, phi, plo);
  attn_kernel<<<1024, 256, 0, stream>>>(qbuf, khi, klo, vthi, vtlo, phi, plo,
                                        ub, vbb, attn, obhi, oblo);
  oproj_mfma<<<dim3(128, 2), 256, 0, stream>>>(obhi, oblo, wsp + 4 * 131072,
                                               bo, out0);
}

// Round 3
// 824.258 us; speedup vs baseline: 3.3967x; 3.3967x over previous
//
#include <hip/hip_runtime.h>
#include <math.h>

// Problem constants
#define TSEQ   1024
#define DMODEL 256
#define NHEAD  8
#define DHEAD  32
#define NREL   2047
#define OUT0   2097152   // B*T*D elements (output 0 size)

// workspace layout (float offsets; ws total = 9,436,672 floats = 37.75 MB)
//  0        : qbuf fp32                     [8][8][1024][32]   8 MB
//  2097152  : K region 8 MB: pehi/pelo (pe_split..pgemm) then khi/klo (proj..attn)
//  4194304  : vthi/vtlo bf16 (transposed)   [8][8][32][1024]x2 8 MB
//  6291456  : phi/plo bf16                  [8][2047][32]x2    2 MB
//  6815488  : O region 8 MB = xhi/xlo (split..proj) then obhi/oblo (attn..oproj)
//  8912640  : wsplit: 5 matrices x (hi 65536 + lo 65536) ushort = 1.25 MB

typedef __attribute__((ext_vector_type(8))) short bf16x8;   // 8 bf16 = 4 VGPRs
typedef __attribute__((ext_vector_type(4))) float f32x4;    // MFMA accumulator

#define MFMA16 __builtin_amdgcn_mfma_f32_16x16x32_bf16

// split fp32 x into bf16 hi + bf16 lo (x ~= hi + lo, dropped part ~2^-18*x)
__device__ __forceinline__ void split2(float x, unsigned short& h, unsigned short& l) {
  unsigned u = __float_as_uint(x);
  unsigned r = (u + 0x7fffu + ((u >> 16) & 1u)) >> 16;   // RNE to bf16
  h = (unsigned short)r;
  float res = x - __uint_as_float(r << 16);
  unsigned u2 = __float_as_uint(res);
  l = (unsigned short)((u2 + 0x7fffu + ((u2 >> 16) & 1u)) >> 16);
}

__device__ __forceinline__ void cvt8(const float* x, bf16x8& h8, bf16x8& l8) {
#pragma unroll
  for (int e = 0; e < 8; ++e) {
    unsigned short a, b;
    split2(x[e], a, b);
    h8[e] = (short)a;
    l8[e] = (short)b;
  }
}

// ---------------------------------------------------------------------------
// One-shot elementwise split: X -> xhi/xlo; Wq,Wk,Wv,Wp,Wo -> wsplit.
__global__ __launch_bounds__(256) void split_kernel(
    const float* __restrict__ X, const float* __restrict__ Wq,
    const float* __restrict__ Wk, const float* __restrict__ Wv,
    const float* __restrict__ Wp, const float* __restrict__ Wo,
    unsigned short* __restrict__ xhi, unsigned short* __restrict__ xlo,
    unsigned short* __restrict__ wsp)
{
  const int idx = blockIdx.x * 256 + threadIdx.x;   // one float4 each
  const float* src;
  unsigned short *dh, *dl;
  int e;
  if (idx < 524288) {               // X: 2,097,152 floats
    src = X; e = idx; dh = xhi; dl = xlo;
  } else {                          // W: 5 x 65536 floats
    const int j = idx - 524288;
    const int m = j >> 14;          // 16384 float4 per matrix
    e = j & 16383;
    src = m == 0 ? Wq : m == 1 ? Wk : m == 2 ? Wv : m == 3 ? Wp : Wo;
    dh = wsp + m * 131072;
    dl = dh + 65536;
  }
  const float4 v = ((const float4*)src)[e];
  unsigned short h0, l0, h1, l1, h2, l2, h3, l3;
  split2(v.x, h0, l0); split2(v.y, h1, l1);
  split2(v.z, h2, l2); split2(v.w, h3, l3);
  ((ushort4*)dh)[e] = make_ushort4(h0, h1, h2, h3);
  ((ushort4*)dl)[e] = make_ushort4(l0, l1, l2, l3);
}

// ---------------------------------------------------------------------------
// Sinusoidal relative PE table, emitted pre-split bf16 hi/lo.
// One trig call per thread, 2047 blocks -> latency spread across the chip.
__global__ __launch_bounds__(256) void pe_split_kernel(
    unsigned short* __restrict__ pehi, unsigned short* __restrict__ pelo)
{
  const int idx = blockIdx.x * 256 + threadIdx.x;
  const int r = idx >> 8;
  const int col = idx & 255;
  const int m2 = col >> 1;
  // denom = 10000^(-m/128) = 2^(-m * log2(1e4)/128)
  const float denom = exp2f((float)m2 * -0.10381025296523007f);
  const float ang = (float)(r - 1023) * denom;
  const float v = (col & 1) ? cosf(ang) : sinf(ang);
  unsigned short h, l;
  split2(v, h, l);
  pehi[idx] = h;
  pelo[idx] = l;
}

// ---------------------------------------------------------------------------
// MFMA QKV projection. No LDS, no barriers: A (X-split) and B (W-split) frags
// are contiguous bf16x8 global loads. Block = 64 rows x 128 cols, 4 waves
// (wave w -> rows 16w..16w+15, 8 col-tiles). grid (128, 6): y>>1 = sel.
// Q written fp32 [bh][t][d]; K split [bh][t][d]; V split TRANSPOSED [bh][d][t].
__global__ __launch_bounds__(256) void proj_qkv_mfma(
    const unsigned short* __restrict__ xhi, const unsigned short* __restrict__ xlo,
    const unsigned short* __restrict__ wsp,
    const float* __restrict__ bq, const float* __restrict__ bk, const float* __restrict__ bv,
    float* __restrict__ qbuf,
    unsigned short* __restrict__ khi, unsigned short* __restrict__ klo,
    unsigned short* __restrict__ vthi, unsigned short* __restrict__ vtlo)
{
  const int sel = blockIdx.y >> 1;
  const int c0  = (blockIdx.y & 1) * 128;
  const int bt0 = blockIdx.x * 64;
  const int tid = threadIdx.x;
  const int w = tid >> 6, lane = tid & 63, lc = lane & 15, lg = lane >> 4;
  const unsigned short* wh = wsp + sel * 131072;
  const unsigned short* wl = wh + 65536;
  const float* bia = sel == 0 ? bq : (sel == 1 ? bk : bv);

  const int arow = bt0 + 16 * w + lc;
  bf16x8 ah[8], al[8];
#pragma unroll
  for (int ks = 0; ks < 8; ++ks) {
    const size_t o = (size_t)arow * 256 + ks * 32 + 8 * lg;
    ah[ks] = *(const bf16x8*)&xhi[o];
    al[ks] = *(const bf16x8*)&xlo[o];
  }
  const f32x4 zf = {0.f, 0.f, 0.f, 0.f};
  for (int ct = 0; ct < 8; ++ct) {
    const int n = c0 + ct * 16 + lc;
    f32x4 acc = zf;
#pragma unroll
    for (int ks = 0; ks < 8; ++ks) {
      const size_t o = (size_t)n * 256 + ks * 32 + 8 * lg;
      const bf16x8 bh8 = *(const bf16x8*)&wh[o];
      const bf16x8 bl8 = *(const bf16x8*)&wl[o];
      acc = MFMA16(ah[ks], bh8, acc, 0, 0, 0);
      acc = MFMA16(al[ks], bh8, acc, 0, 0, 0);
      acc = MFMA16(ah[ks], bl8, acc, 0, 0, 0);
    }
    const float bz = bia[n];
    const int hh = n >> 5, dd = n & 31;
#pragma unroll
    for (int r = 0; r < 4; ++r) {
      const int bt = bt0 + 16 * w + 4 * lg + r;
      const int bb = bt >> 10, t = bt & 1023;
      const float val = acc[r] + bz;
      if (sel == 0) {
        qbuf[(((size_t)bb * NHEAD + hh) * TSEQ + t) * DHEAD + dd] = val;
      } else if (sel == 1) {
        unsigned short a2, b2; split2(val, a2, b2);
        const size_t o2 = (((size_t)bb * NHEAD + hh) * TSEQ + t) * DHEAD + dd;
        khi[o2] = a2; klo[o2] = b2;
      } else {
        unsigned short a2, b2; split2(val, a2, b2);
        const size_t o2 = (((size_t)bb * NHEAD + hh) * DHEAD + dd) * TSEQ + t;
        vthi[o2] = a2; vtlo[o2] = b2;
      }
    }
  }
}

// ---------------------------------------------------------------------------
// MFMA P projection: A frags loaded from the pre-split PE table (no trig).
// grid (32, 2). Must run BEFORE proj_qkv_mfma (pe table aliases the K region).
__global__ __launch_bounds__(256) void pgemm_mfma(
    const unsigned short* __restrict__ pehi, const unsigned short* __restrict__ pelo,
    const unsigned short* __restrict__ wph,
    unsigned short* __restrict__ phi, unsigned short* __restrict__ plo)
{
  const unsigned short* wpl = wph + 65536;
  const int bt0 = blockIdx.x * 64;
  const int c0  = blockIdx.y * 128;
  const int tid = threadIdx.x;
  const int w = tid >> 6, lane = tid & 63, lc = lane & 15, lg = lane >> 4;

  int prow = bt0 + 16 * w + lc;
  if (prow > 2046) prow = 2046;          // row 2047 output is discarded anyway
  bf16x8 ah[8], al[8];
#pragma unroll
  for (int ks = 0; ks < 8; ++ks) {
    const size_t o = (size_t)prow * 256 + ks * 32 + 8 * lg;
    ah[ks] = *(const bf16x8*)&pehi[o];
    al[ks] = *(const bf16x8*)&pelo[o];
  }
  const f32x4 zf = {0.f, 0.f, 0.f, 0.f};
  for (int ct = 0; ct < 8; ++ct) {
    const int n = c0 + ct * 16 + lc;
    f32x4 acc = zf;
#pragma unroll
    for (int ks = 0; ks < 8; ++ks) {
      const size_t o = (size_t)n * 256 + ks * 32 + 8 * lg;
      const bf16x8 bh8 = *(const bf16x8*)&wph[o];
      const bf16x8 bl8 = *(const bf16x8*)&wpl[o];
      acc = MFMA16(ah[ks], bh8, acc, 0, 0, 0);
      acc = MFMA16(al[ks], bh8, acc, 0, 0, 0);
      acc = MFMA16(ah[ks], bl8, acc, 0, 0, 0);
    }
    const int hh = n >> 5, dd = n & 31;
#pragma unroll
    for (int r = 0; r < 4; ++r) {
      const int rr2 = bt0 + 16 * w + 4 * lg + r;
      if (rr2 < NREL) {
        unsigned short a2, b2;
        split2(acc[r], a2, b2);
        const size_t o2 = ((size_t)hh * NREL + rr2) * DHEAD + dd;
        phi[o2] = a2; plo[o2] = b2;
      }
    }
  }
}

// ---------------------------------------------------------------------------
// MFMA attention. One block = (b,h, 64-row i-tile); 4 waves; LDS 51.2 KB ->
// 3 blocks/CU. V read as pre-split transposed bf16 straight from global,
// prefetched at tile start so latency hides under the M/S MFMA recompute.
// obuf written pre-split bf16 hi/lo.
__global__ __launch_bounds__(256, 3) void attn_kernel(
    const float* __restrict__ qbuf,
    const unsigned short* __restrict__ khi, const unsigned short* __restrict__ klo,
    const unsigned short* __restrict__ vthi, const unsigned short* __restrict__ vtlo,
    const unsigned short* __restrict__ phi, const unsigned short* __restrict__ plo,
    const float* __restrict__ ub, const float* __restrict__ vbias,
    float* __restrict__ attn_out,
    unsigned short* __restrict__ obhi, unsigned short* __restrict__ oblo)
{
  __shared__ float smem[12800];          // 51.2 KB
  float* const Mlds = smem;              // [64][132] M chunk
  float* const Pt   = smem + 8448;       // [64][68]  probs tile

  const int orig = blockIdx.x;
  const int blk  = (orig & 7) * 128 + (orig >> 3);   // XCD swizzle (1024 % 8 == 0)
  const int bh   = blk >> 4;
  const int i0   = (blk & 15) << 6;
  const int h    = bh & 7;
  const int bb   = bh >> 3;
  const int tid  = threadIdx.x;
  const int w    = tid >> 6;             // wave 0..3
  const int lane = tid & 63;
  const int lc   = lane & 15;            // A row / B col within 16-subtile
  const int lg   = lane >> 4;            // k-group (8 elems each)

  const float* __restrict__ qrow = qbuf + (size_t)bh * (TSEQ * DHEAD);
  const unsigned short* __restrict__ kh = khi + (size_t)bh * (TSEQ * DHEAD);
  const unsigned short* __restrict__ kl = klo + (size_t)bh * (TSEQ * DHEAD);
  const unsigned short* __restrict__ vth = vthi + (size_t)bh * (DHEAD * TSEQ);
  const unsigned short* __restrict__ vtl = vtlo + (size_t)bh * (DHEAD * TSEQ);
  const unsigned short* __restrict__ ph_ = phi + (size_t)h * ((size_t)NREL * DHEAD);
  const unsigned short* __restrict__ pl_ = plo + (size_t)h * ((size_t)NREL * DHEAD);
  float* __restrict__ arow = attn_out + (size_t)bh * ((size_t)TSEQ * TSEQ);

  // ---- prologue: build qu/qv A-fragments (row = lc, k = 8*lg + e) ----
  bf16x8 quh, qul, qvh, qvl;
  {
    float q8[8];
    const float* qp = &qrow[(size_t)(i0 + 16 * w + lc) * DHEAD + 8 * lg];
    *(float4*)&q8[0] = *(const float4*)&qp[0];
    *(float4*)&q8[4] = *(const float4*)&qp[4];
#pragma unroll
    for (int e = 0; e < 8; ++e) {
      const float uu = ub[h * DHEAD + 8 * lg + e];
      const float vv = vbias[h * DHEAD + 8 * lg + e];
      unsigned short a, b;
      split2(q8[e] + uu, a, b); quh[e] = (short)a; qul[e] = (short)b;
      split2(q8[e] + vv, a, b); qvh[e] = (short)a; qvl[e] = (short)b;
    }
  }

  const float KSC = 0.09016844136f;      // 1/(sqrt(256)*ln2)
  float m_l[4], sm_l[4];
#pragma unroll
  for (int r = 0; r < 4; ++r) { m_l[r] = -1e30f; sm_l[r] = 0.f; }

  const f32x4 zf = {0.f, 0.f, 0.f, 0.f};

  // ================= sweep 1: stats =================
  for (int t = 0; t < 16; ++t) {
    const int j0 = t * 64;
    const int r0 = i0 - j0 + 960;        // first P row of this tile's M chunk
    f32x4 mf[8];
#pragma unroll
    for (int st = 0; st < 8; ++st) mf[st] = zf;
#pragma unroll
    for (int st = 0; st < 8; ++st) {
      int pr = r0 + 16 * st + lc;
      if (pr > 2046) pr = 2046;
      const size_t o = (size_t)pr * DHEAD + 8 * lg;
      const bf16x8 bh8 = *(const bf16x8*)&ph_[o];
      const bf16x8 bl8 = *(const bf16x8*)&pl_[o];
      mf[st] = MFMA16(qvh, bh8, mf[st], 0, 0, 0);
      mf[st] = MFMA16(qvl, bh8, mf[st], 0, 0, 0);
      mf[st] = MFMA16(qvh, bl8, mf[st], 0, 0, 0);
    }
    __syncthreads();                     // prev-tile gather finished
#pragma unroll
    for (int st = 0; st < 8; ++st)
#pragma unroll
      for (int r = 0; r < 4; ++r)
        Mlds[(16 * w + 4 * lg + r) * 132 + 16 * st + lc] = mf[st][r];

    f32x4 sf[4];
#pragma unroll
    for (int st = 0; st < 4; ++st) sf[st] = zf;
#pragma unroll
    for (int st = 0; st < 4; ++st) {
      const size_t o = (size_t)(j0 + 16 * st + lc) * DHEAD + 8 * lg;
      const bf16x8 bh8 = *(const bf16x8*)&kh[o];
      const bf16x8 bl8 = *(const bf16x8*)&kl[o];
      sf[st] = MFMA16(quh, bh8, sf[st], 0, 0, 0);
      sf[st] = MFMA16(qul, bh8, sf[st], 0, 0, 0);
      sf[st] = MFMA16(quh, bl8, sf[st], 0, 0, 0);
    }
    __syncthreads();                     // M chunk visible
#pragma unroll
    for (int st = 0; st < 4; ++st) {
      const int jloc = 16 * st + lc;
#pragma unroll
      for (int r = 0; r < 4; ++r) {
        const int il = 16 * w + 4 * lg + r;
        sf[st][r] += Mlds[il * 132 + (il - jloc + 63)];
      }
    }
#pragma unroll
    for (int r = 0; r < 4; ++r) {
      const float t0 = fmaxf(fmaxf(sf[0][r], sf[1][r]), fmaxf(sf[2][r], sf[3][r]));
      const float mn = fmaxf(m_l[r], t0);
      const float ps = exp2f((sf[0][r] - mn) * KSC) + exp2f((sf[1][r] - mn) * KSC)
                     + exp2f((sf[2][r] - mn) * KSC) + exp2f((sf[3][r] - mn) * KSC);
      sm_l[r] = sm_l[r] * exp2f((m_l[r] - mn) * KSC) + ps;
      m_l[r] = mn;
    }
  }

  // merge stats across the 16-lane row group
  float m_f[4], rs[4];
#pragma unroll
  for (int r = 0; r < 4; ++r) {
    float mm = m_l[r], ss = sm_l[r];
#pragma unroll
    for (int d = 1; d < 16; d <<= 1) {
      const float om = __shfl_xor(mm, d);
      const float os = __shfl_xor(ss, d);
      const float M2 = fmaxf(mm, om);
      ss = ss * exp2f((mm - M2) * KSC) + os * exp2f((om - M2) * KSC);
      mm = M2;
    }
    m_f[r] = mm;
    rs[r] = 1.0f / ss;
  }

  // ================= sweep 2: probs + AV =================
  f32x4 of0 = zf, of1 = zf;
  for (int t = 0; t < 16; ++t) {
    const int j0 = t * 64;
    const int r0 = i0 - j0 + 960;

    // prefetch vT B-frags early: latency hides under the 36-MFMA recompute
    const size_t vo0 = (size_t)lc * TSEQ + j0 + 8 * lg;         // d = lc
    const size_t vo1 = (size_t)(lc + 16) * TSEQ + j0 + 8 * lg;  // d = lc+16
    const bf16x8 v00h = *(const bf16x8*)&vth[vo0];
    const bf16x8 v00l = *(const bf16x8*)&vtl[vo0];
    const bf16x8 v01h = *(const bf16x8*)&vth[vo1];
    const bf16x8 v01l = *(const bf16x8*)&vtl[vo1];
    const bf16x8 v10h = *(const bf16x8*)&vth[vo0 + 32];
    const bf16x8 v10l = *(const bf16x8*)&vtl[vo0 + 32];
    const bf16x8 v11h = *(const bf16x8*)&vth[vo1 + 32];
    const bf16x8 v11l = *(const bf16x8*)&vtl[vo1 + 32];

    f32x4 mf[8];
#pragma unroll
    for (int st = 0; st < 8; ++st) mf[st] = zf;
#pragma unroll
    for (int st = 0; st < 8; ++st) {
      int pr = r0 + 16 * st + lc;
      if (pr > 2046) pr = 2046;
      const size_t o = (size_t)pr * DHEAD + 8 * lg;
      const bf16x8 bh8 = *(const bf16x8*)&ph_[o];
      const bf16x8 bl8 = *(const bf16x8*)&pl_[o];
      mf[st] = MFMA16(qvh, bh8, mf[st], 0, 0, 0);
      mf[st] = MFMA16(qvl, bh8, mf[st], 0, 0, 0);
      mf[st] = MFMA16(qvh, bl8, mf[st], 0, 0, 0);
    }
    __syncthreads();                     // A: prev tile's Pt reads done
#pragma unroll
    for (int st = 0; st < 8; ++st)
#pragma unroll
      for (int r = 0; r < 4; ++r)
        Mlds[(16 * w + 4 * lg + r) * 132 + 16 * st + lc] = mf[st][r];

    f32x4 sf[4];
#pragma unroll
    for (int st = 0; st < 4; ++st) sf[st] = zf;
#pragma unroll
    for (int st = 0; st < 4; ++st) {
      const size_t o = (size_t)(j0 + 16 * st + lc) * DHEAD + 8 * lg;
      const bf16x8 bh8 = *(const bf16x8*)&kh[o];
      const bf16x8 bl8 = *(const bf16x8*)&kl[o];
      sf[st] = MFMA16(quh, bh8, sf[st], 0, 0, 0);
      sf[st] = MFMA16(qul, bh8, sf[st], 0, 0, 0);
      sf[st] = MFMA16(quh, bl8, sf[st], 0, 0, 0);
    }
    __syncthreads();                     // B: M chunk visible

#pragma unroll
    for (int st = 0; st < 4; ++st) {
      const int jloc = 16 * st + lc;
#pragma unroll
      for (int r = 0; r < 4; ++r) {
        const int il = 16 * w + 4 * lg + r;
        const float sv = sf[st][r] + Mlds[il * 132 + (il - jloc + 63)];
        const float p = exp2f((sv - m_f[r]) * KSC) * rs[r];
        Pt[il * 68 + jloc] = p;
      }
    }
    __syncthreads();                     // C: probs tile complete
    // global attn store (256B runs per row quarter)
    {
      const int prow = tid >> 2, cb = (tid & 3) * 16;
      float* gp = &arow[(size_t)(i0 + prow) * TSEQ + j0 + cb];
      const float* sp = &Pt[prow * 68 + cb];
#pragma unroll
      for (int qq = 0; qq < 4; ++qq)
        *(float4*)&gp[qq * 4] = *(const float4*)&sp[qq * 4];
    }
    // AV: O[16x32] += probs(16x64) x V(64x32); V frags already in registers
#pragma unroll
    for (int kc = 0; kc < 2; ++kc) {
      float tmp[8];
      const float* ap = &Pt[(16 * w + lc) * 68 + 32 * kc + 8 * lg];
      *(float4*)&tmp[0] = *(const float4*)&ap[0];
      *(float4*)&tmp[4] = *(const float4*)&ap[4];
      bf16x8 pah, pal;
      cvt8(tmp, pah, pal);
      const bf16x8 b0h = kc ? v10h : v00h;
      const bf16x8 b0l = kc ? v10l : v00l;
      const bf16x8 b1h = kc ? v11h : v01h;
      const bf16x8 b1l = kc ? v11l : v01l;
      of0 = MFMA16(pah, b0h, of0, 0, 0, 0);
      of0 = MFMA16(pal, b0h, of0, 0, 0, 0);
      of0 = MFMA16(pah, b0l, of0, 0, 0, 0);
      of1 = MFMA16(pah, b1h, of1, 0, 0, 0);
      of1 = MFMA16(pal, b1h, of1, 0, 0, 0);
      of1 = MFMA16(pah, b1l, of1, 0, 0, 0);
    }
  }

  // write O head slice pre-split for MFMA oproj
#pragma unroll
  for (int r = 0; r < 4; ++r) {
    const int row = i0 + 16 * w + 4 * lg + r;
    const size_t base = ((size_t)bb * TSEQ + row) * DMODEL + h * DHEAD;
    unsigned short a2, b2;
    split2(of0[r], a2, b2); obhi[base + lc]      = a2; oblo[base + lc]      = b2;
    split2(of1[r], a2, b2); obhi[base + lc + 16] = a2; oblo[base + lc + 16] = b2;
  }
}

// ---------------------------------------------------------------------------
// MFMA output projection: obuf-split x Wo-split + bo -> out0 fp32.
__global__ __launch_bounds__(256) void oproj_mfma(
    const unsigned short* __restrict__ obhi, const unsigned short* __restrict__ oblo,
    const unsigned short* __restrict__ woh,
    const float* __restrict__ bo, float* __restrict__ out)
{
  const unsigned short* wol = woh + 65536;
  const int c0  = blockIdx.y * 128;
  const int bt0 = blockIdx.x * 64;
  const int tid = threadIdx.x;
  const int w = tid >> 6, lane = tid & 63, lc = lane & 15, lg = lane >> 4;

  const int arow = bt0 + 16 * w + lc;
  bf16x8 ah[8], al[8];
#pragma unroll
  for (int ks = 0; ks < 8; ++ks) {
    const size_t o = (size_t)arow * 256 + ks * 32 + 8 * lg;
    ah[ks] = *(const bf16x8*)&obhi[o];
    al[ks] = *(const bf16x8*)&oblo[o];
  }
  const f32x4 zf = {0.f, 0.f, 0.f, 0.f};
  for (int ct = 0; ct < 8; ++ct) {
    const int n = c0 + ct * 16 + lc;
    f32x4 acc = zf;
#pragma unroll
    for (int ks = 0; ks < 8; ++ks) {
      const size_t o = (size_t)n * 256 + ks * 32 + 8 * lg;
      const bf16x8 bh8 = *(const bf16x8*)&woh[o];
      const bf16x8 bl8 = *(const bf16x8*)&wol[o];
      acc = MFMA16(ah[ks], bh8, acc, 0, 0, 0);
      acc = MFMA16(al[ks], bh8, acc, 0, 0, 0);
      acc = MFMA16(ah[ks], bl8, acc, 0, 0, 0);
    }
    const float bz = bo[n];
#pragma unroll
    for (int r = 0; r < 4; ++r) {
      const int bt = bt0 + 16 * w + 4 * lg + r;
      out[(size_t)bt * DMODEL + n] = acc[r] + bz;
    }
  }
}

// ---------------------------------------------------------------------------
extern "C" void kernel_launch(void* const* d_in, const int* in_sizes, int n_in,
                              void* d_out, int out_size, void* d_ws, size_t ws_size,
                              hipStream_t stream) {
  const float* X   = (const float*)d_in[0];
  const float* Wq  = (const float*)d_in[1];
  const float* bq  = (const float*)d_in[2];
  const float* Wk  = (const float*)d_in[3];
  const float* bk  = (const float*)d_in[4];
  const float* Wv  = (const float*)d_in[5];
  const float* bv  = (const float*)d_in[6];
  const float* Wp  = (const float*)d_in[7];
  const float* Wo  = (const float*)d_in[8];
  const float* bo  = (const float*)d_in[9];
  const float* ub  = (const float*)d_in[10];
  const float* vbb = (const float*)d_in[11];

  float* ws = (float*)d_ws;
  float* qbuf = ws;                                          // fp32 Q
  unsigned short* khi  = (unsigned short*)(ws + 2097152u);
  unsigned short* klo  = khi + 2097152u;
  unsigned short* pehi = khi;            // alias: pe table dead before K write
  unsigned short* pelo = pehi + 524032u;
  unsigned short* vthi = (unsigned short*)(ws + 4194304u);
  unsigned short* vtlo = vthi + 2097152u;
  unsigned short* phi  = (unsigned short*)(ws + 6291456u);
  unsigned short* plo  = phi + 524032u;
  unsigned short* obhi = (unsigned short*)(ws + 6815488u);   // O region
  unsigned short* oblo = obhi + 2097152u;
  unsigned short* xhi  = obhi;   // alias: X-split dead before attn writes obuf
  unsigned short* xlo  = oblo;
  unsigned short* wsp  = (unsigned short*)(ws + 8912640u);   // 5x(hi+lo) W split

  float* out0 = (float*)d_out;
  float* attn = out0 + OUT0;

  split_kernel<<<2368, 256, 0, stream>>>(X, Wq, Wk, Wv, Wp, Wo, xhi, xlo, wsp);
  pe_split_kernel<<<2047, 256, 0, stream>>>(pehi, pelo);
  pgemm_mfma<<<dim3(32, 2), 256, 0, stream>>>(pehi, pelo, wsp + 3 * 131072,
                                              phi, plo);
  proj_qkv_mfma<<<dim3(128, 6), 256, 0, stream>>>(xhi, xlo, wsp, bq, bk, bv,
                                                  qbuf, khi, klo, vthi, vtlo);
  attn_kernel<<<1024, 256, 0, stream>>>(qbuf, khi, klo, vthi, vtlo, phi, plo,
                                        ub, vbb, attn, obhi, oblo);
  oproj_mfma<<<dim3(128, 2), 256, 0, stream>>>(obhi, oblo, wsp + 4 * 131072,
                                               bo, out0);
}

// Round 4
// 687.213 us; speedup vs baseline: 4.0740x; 1.1994x over previous
//
#include <hip/hip_runtime.h>
#include <math.h>

// Problem constants
#define TSEQ   1024
#define DMODEL 256
#define NHEAD  8
#define DHEAD  32
#define NREL   2047
#define OUT0   2097152   // B*T*D elements (output 0 size)

// workspace layout (float offsets; ws total = 9,436,672 floats = 37.75 MB)
//  0        : qbuf fp32                     [8][8][1024][32]   8 MB
//  2097152  : K region 8 MB: pehi/pelo (prep..pgemm) then khi/klo (proj..attn)
//  4194304  : vthi/vtlo bf16 (transposed)   [8][8][32][1024]x2 8 MB
//  6291456  : phi/plo bf16                  [8][2047][32]x2    2 MB
//  6815488  : O region 8 MB = xhi/xlo (prep..proj) then obhi/oblo (attn..oproj)
//  8912640  : wsplit: 5 matrices x (hi 65536 + lo 65536) ushort = 1.25 MB

typedef __attribute__((ext_vector_type(8))) short bf16x8;   // 8 bf16 = 4 VGPRs
typedef __attribute__((ext_vector_type(4))) float f32x4;    // MFMA accumulator

#define MFMA16 __builtin_amdgcn_mfma_f32_16x16x32_bf16

// split fp32 x into bf16 hi + bf16 lo (x ~= hi + lo, dropped part ~2^-18*x)
__device__ __forceinline__ void split2(float x, unsigned short& h, unsigned short& l) {
  unsigned u = __float_as_uint(x);
  unsigned r = (u + 0x7fffu + ((u >> 16) & 1u)) >> 16;   // RNE to bf16
  h = (unsigned short)r;
  float res = x - __uint_as_float(r << 16);
  unsigned u2 = __float_as_uint(res);
  l = (unsigned short)((u2 + 0x7fffu + ((u2 >> 16) & 1u)) >> 16);
}

__device__ __forceinline__ void cvt8(const float* x, bf16x8& h8, bf16x8& l8) {
#pragma unroll
  for (int e = 0; e < 8; ++e) {
    unsigned short a, b;
    split2(x[e], a, b);
    h8[e] = (short)a;
    l8[e] = (short)b;
  }
}

// ---------------------------------------------------------------------------
// Prep: elementwise split of X and the 5 weight matrices + sinusoidal PE table
// emitted pre-split. One kernel launch (blocks < 2368: split; >= 2368: PE).
__global__ __launch_bounds__(256) void prep_kernel(
    const float* __restrict__ X, const float* __restrict__ Wq,
    const float* __restrict__ Wk, const float* __restrict__ Wv,
    const float* __restrict__ Wp, const float* __restrict__ Wo,
    unsigned short* __restrict__ xhi, unsigned short* __restrict__ xlo,
    unsigned short* __restrict__ wsp,
    unsigned short* __restrict__ pehi, unsigned short* __restrict__ pelo)
{
  if (blockIdx.x >= 2368) {   // ---- PE table: 2047*256 elements ----
    const int idx = (blockIdx.x - 2368) * 256 + threadIdx.x;
    const int r = idx >> 8;
    const int col = idx & 255;
    const int m2 = col >> 1;
    // denom = 10000^(-m/128) = 2^(-m * log2(1e4)/128)
    const float denom = exp2f((float)m2 * -0.10381025296523007f);
    const float ang = (float)(r - 1023) * denom;
    const float v = (col & 1) ? cosf(ang) : sinf(ang);
    unsigned short h, l;
    split2(v, h, l);
    pehi[idx] = h;
    pelo[idx] = l;
    return;
  }
  const int idx = blockIdx.x * 256 + threadIdx.x;   // one float4 each
  const float* src;
  unsigned short *dh, *dl;
  int e;
  if (idx < 524288) {               // X: 2,097,152 floats
    src = X; e = idx; dh = xhi; dl = xlo;
  } else {                          // W: 5 x 65536 floats
    const int j = idx - 524288;
    const int m = j >> 14;          // 16384 float4 per matrix
    e = j & 16383;
    src = m == 0 ? Wq : m == 1 ? Wk : m == 2 ? Wv : m == 3 ? Wp : Wo;
    dh = wsp + m * 131072;
    dl = dh + 65536;
  }
  const float4 v = ((const float4*)src)[e];
  unsigned short h0, l0, h1, l1, h2, l2, h3, l3;
  split2(v.x, h0, l0); split2(v.y, h1, l1);
  split2(v.z, h2, l2); split2(v.w, h3, l3);
  ((ushort4*)dh)[e] = make_ushort4(h0, h1, h2, h3);
  ((ushort4*)dl)[e] = make_ushort4(l0, l1, l2, l3);
}

// ---------------------------------------------------------------------------
// MFMA QKV projection. No LDS, no barriers: A (X-split) and B (W-split) frags
// are contiguous bf16x8 global loads. Block = 64 rows x 128 cols, 4 waves.
// grid (128, 6): y>>1 = sel. Q fp32 [bh][t][d]; K split [bh][t][d];
// V split TRANSPOSED [bh][d][t].
__global__ __launch_bounds__(256) void proj_qkv_mfma(
    const unsigned short* __restrict__ xhi, const unsigned short* __restrict__ xlo,
    const unsigned short* __restrict__ wsp,
    const float* __restrict__ bq, const float* __restrict__ bk, const float* __restrict__ bv,
    float* __restrict__ qbuf,
    unsigned short* __restrict__ khi, unsigned short* __restrict__ klo,
    unsigned short* __restrict__ vthi, unsigned short* __restrict__ vtlo)
{
  const int sel = blockIdx.y >> 1;
  const int c0  = (blockIdx.y & 1) * 128;
  const int bt0 = blockIdx.x * 64;
  const int tid = threadIdx.x;
  const int w = tid >> 6, lane = tid & 63, lc = lane & 15, lg = lane >> 4;
  const unsigned short* wh = wsp + sel * 131072;
  const unsigned short* wl = wh + 65536;
  const float* bia = sel == 0 ? bq : (sel == 1 ? bk : bv);

  const int arow = bt0 + 16 * w + lc;
  bf16x8 ah[8], al[8];
#pragma unroll
  for (int ks = 0; ks < 8; ++ks) {
    const size_t o = (size_t)arow * 256 + ks * 32 + 8 * lg;
    ah[ks] = *(const bf16x8*)&xhi[o];
    al[ks] = *(const bf16x8*)&xlo[o];
  }
  const f32x4 zf = {0.f, 0.f, 0.f, 0.f};
  for (int ct = 0; ct < 8; ++ct) {
    const int n = c0 + ct * 16 + lc;
    f32x4 acc = zf;
#pragma unroll
    for (int ks = 0; ks < 8; ++ks) {
      const size_t o = (size_t)n * 256 + ks * 32 + 8 * lg;
      const bf16x8 bh8 = *(const bf16x8*)&wh[o];
      const bf16x8 bl8 = *(const bf16x8*)&wl[o];
      acc = MFMA16(ah[ks], bh8, acc, 0, 0, 0);
      acc = MFMA16(al[ks], bh8, acc, 0, 0, 0);
      acc = MFMA16(ah[ks], bl8, acc, 0, 0, 0);
    }
    const float bz = bia[n];
    const int hh = n >> 5, dd = n & 31;
#pragma unroll
    for (int r = 0; r < 4; ++r) {
      const int bt = bt0 + 16 * w + 4 * lg + r;
      const int bb = bt >> 10, t = bt & 1023;
      const float val = acc[r] + bz;
      if (sel == 0) {
        qbuf[(((size_t)bb * NHEAD + hh) * TSEQ + t) * DHEAD + dd] = val;
      } else if (sel == 1) {
        unsigned short a2, b2; split2(val, a2, b2);
        const size_t o2 = (((size_t)bb * NHEAD + hh) * TSEQ + t) * DHEAD + dd;
        khi[o2] = a2; klo[o2] = b2;
      } else {
        unsigned short a2, b2; split2(val, a2, b2);
        const size_t o2 = (((size_t)bb * NHEAD + hh) * DHEAD + dd) * TSEQ + t;
        vthi[o2] = a2; vtlo[o2] = b2;
      }
    }
  }
}

// ---------------------------------------------------------------------------
// MFMA P projection: A frags loaded from the pre-split PE table (no trig).
// grid (32, 2). Must run BEFORE proj_qkv_mfma (pe table aliases the K region).
__global__ __launch_bounds__(256) void pgemm_mfma(
    const unsigned short* __restrict__ pehi, const unsigned short* __restrict__ pelo,
    const unsigned short* __restrict__ wph,
    unsigned short* __restrict__ phi, unsigned short* __restrict__ plo)
{
  const unsigned short* wpl = wph + 65536;
  const int bt0 = blockIdx.x * 64;
  const int c0  = blockIdx.y * 128;
  const int tid = threadIdx.x;
  const int w = tid >> 6, lane = tid & 63, lc = lane & 15, lg = lane >> 4;

  int prow = bt0 + 16 * w + lc;
  if (prow > 2046) prow = 2046;          // row 2047 output is discarded anyway
  bf16x8 ah[8], al[8];
#pragma unroll
  for (int ks = 0; ks < 8; ++ks) {
    const size_t o = (size_t)prow * 256 + ks * 32 + 8 * lg;
    ah[ks] = *(const bf16x8*)&pehi[o];
    al[ks] = *(const bf16x8*)&pelo[o];
  }
  const f32x4 zf = {0.f, 0.f, 0.f, 0.f};
  for (int ct = 0; ct < 8; ++ct) {
    const int n = c0 + ct * 16 + lc;
    f32x4 acc = zf;
#pragma unroll
    for (int ks = 0; ks < 8; ++ks) {
      const size_t o = (size_t)n * 256 + ks * 32 + 8 * lg;
      const bf16x8 bh8 = *(const bf16x8*)&wph[o];
      const bf16x8 bl8 = *(const bf16x8*)&wpl[o];
      acc = MFMA16(ah[ks], bh8, acc, 0, 0, 0);
      acc = MFMA16(al[ks], bh8, acc, 0, 0, 0);
      acc = MFMA16(ah[ks], bl8, acc, 0, 0, 0);
    }
    const int hh = n >> 5, dd = n & 31;
#pragma unroll
    for (int r = 0; r < 4; ++r) {
      const int rr2 = bt0 + 16 * w + 4 * lg + r;
      if (rr2 < NREL) {
        unsigned short a2, b2;
        split2(acc[r], a2, b2);
        const size_t o2 = ((size_t)hh * NREL + rr2) * DHEAD + dd;
        phi[o2] = a2; plo[o2] = b2;
      }
    }
  }
}

// ---------------------------------------------------------------------------
// MFMA attention. One block = (b,h, 64-row i-tile); 4 waves.
// LDS 42 KB (Pt aliases Mlds; V staged pre-split bf16) -> 3 blocks/CU.
// Sweep 2 per tile: V global->regs early; M recompute; [A] Mlds+VT writes;
// S recompute; [B] gather->p regs; [D] Pt write (alias); [C] attn store + AV.
__global__ __launch_bounds__(256, 3) void attn_kernel(
    const float* __restrict__ qbuf,
    const unsigned short* __restrict__ khi, const unsigned short* __restrict__ klo,
    const unsigned short* __restrict__ vthi, const unsigned short* __restrict__ vtlo,
    const unsigned short* __restrict__ phi, const unsigned short* __restrict__ plo,
    const float* __restrict__ ub, const float* __restrict__ vbias,
    float* __restrict__ attn_out,
    unsigned short* __restrict__ obhi, unsigned short* __restrict__ oblo)
{
  __shared__ float smem[10752];          // 43008 B -> 3 blocks/CU
  float* const Mlds = smem;              // [64][132] M chunk (8448 floats)
  float* const Pt   = smem;              // [64][68] probs tile (ALIASES Mlds)
  unsigned short* const VTh = (unsigned short*)(smem + 8448);  // [32][72]
  unsigned short* const VTl = VTh + 2304;                      // [32][72]

  const int orig = blockIdx.x;
  const int blk  = (orig & 7) * 128 + (orig >> 3);   // XCD swizzle (1024 % 8 == 0)
  const int bh   = blk >> 4;
  const int i0   = (blk & 15) << 6;
  const int h    = bh & 7;
  const int bb   = bh >> 3;
  const int tid  = threadIdx.x;
  const int w    = tid >> 6;             // wave 0..3
  const int lane = tid & 63;
  const int lc   = lane & 15;            // A row / B col within 16-subtile
  const int lg   = lane >> 4;            // k-group (8 elems each)

  const float* __restrict__ qrow = qbuf + (size_t)bh * (TSEQ * DHEAD);
  const unsigned short* __restrict__ kh = khi + (size_t)bh * (TSEQ * DHEAD);
  const unsigned short* __restrict__ kl = klo + (size_t)bh * (TSEQ * DHEAD);
  const unsigned short* __restrict__ vth = vthi + (size_t)bh * (DHEAD * TSEQ);
  const unsigned short* __restrict__ vtl = vtlo + (size_t)bh * (DHEAD * TSEQ);
  const unsigned short* __restrict__ ph_ = phi + (size_t)h * ((size_t)NREL * DHEAD);
  const unsigned short* __restrict__ pl_ = plo + (size_t)h * ((size_t)NREL * DHEAD);
  float* __restrict__ arow = attn_out + (size_t)bh * ((size_t)TSEQ * TSEQ);

  // ---- prologue: build qu/qv A-fragments (row = lc, k = 8*lg + e) ----
  bf16x8 quh, qul, qvh, qvl;
  {
    float q8[8];
    const float* qp = &qrow[(size_t)(i0 + 16 * w + lc) * DHEAD + 8 * lg];
    *(float4*)&q8[0] = *(const float4*)&qp[0];
    *(float4*)&q8[4] = *(const float4*)&qp[4];
#pragma unroll
    for (int e = 0; e < 8; ++e) {
      const float uu = ub[h * DHEAD + 8 * lg + e];
      const float vv = vbias[h * DHEAD + 8 * lg + e];
      unsigned short a, b;
      split2(q8[e] + uu, a, b); quh[e] = (short)a; qul[e] = (short)b;
      split2(q8[e] + vv, a, b); qvh[e] = (short)a; qvl[e] = (short)b;
    }
  }

  const float KSC = 0.09016844136f;      // 1/(sqrt(256)*ln2)
  float m_l[4], sm_l[4];
#pragma unroll
  for (int r = 0; r < 4; ++r) { m_l[r] = -1e30f; sm_l[r] = 0.f; }

  const f32x4 zf = {0.f, 0.f, 0.f, 0.f};

  // ================= sweep 1: stats =================
  for (int t = 0; t < 16; ++t) {
    const int j0 = t * 64;
    const int r0 = i0 - j0 + 960;        // first P row of this tile's M chunk
    f32x4 mf[8];
#pragma unroll
    for (int st = 0; st < 8; ++st) mf[st] = zf;
#pragma unroll
    for (int st = 0; st < 8; ++st) {
      int pr = r0 + 16 * st + lc;
      if (pr > 2046) pr = 2046;
      const size_t o = (size_t)pr * DHEAD + 8 * lg;
      const bf16x8 bh8 = *(const bf16x8*)&ph_[o];
      const bf16x8 bl8 = *(const bf16x8*)&pl_[o];
      mf[st] = MFMA16(qvh, bh8, mf[st], 0, 0, 0);
      mf[st] = MFMA16(qvl, bh8, mf[st], 0, 0, 0);
      mf[st] = MFMA16(qvh, bl8, mf[st], 0, 0, 0);
    }
    __syncthreads();                     // prev-tile gather finished
#pragma unroll
    for (int st = 0; st < 8; ++st)
#pragma unroll
      for (int r = 0; r < 4; ++r)
        Mlds[(16 * w + 4 * lg + r) * 132 + 16 * st + lc] = mf[st][r];

    f32x4 sf[4];
#pragma unroll
    for (int st = 0; st < 4; ++st) sf[st] = zf;
#pragma unroll
    for (int st = 0; st < 4; ++st) {
      const size_t o = (size_t)(j0 + 16 * st + lc) * DHEAD + 8 * lg;
      const bf16x8 bh8 = *(const bf16x8*)&kh[o];
      const bf16x8 bl8 = *(const bf16x8*)&kl[o];
      sf[st] = MFMA16(quh, bh8, sf[st], 0, 0, 0);
      sf[st] = MFMA16(qul, bh8, sf[st], 0, 0, 0);
      sf[st] = MFMA16(quh, bl8, sf[st], 0, 0, 0);
    }
    __syncthreads();                     // M chunk visible
#pragma unroll
    for (int st = 0; st < 4; ++st) {
      const int jloc = 16 * st + lc;
#pragma unroll
      for (int r = 0; r < 4; ++r) {
        const int il = 16 * w + 4 * lg + r;
        sf[st][r] += Mlds[il * 132 + (il - jloc + 63)];
      }
    }
#pragma unroll
    for (int r = 0; r < 4; ++r) {
      const float t0 = fmaxf(fmaxf(sf[0][r], sf[1][r]), fmaxf(sf[2][r], sf[3][r]));
      const float mn = fmaxf(m_l[r], t0);
      const float ps = exp2f((sf[0][r] - mn) * KSC) + exp2f((sf[1][r] - mn) * KSC)
                     + exp2f((sf[2][r] - mn) * KSC) + exp2f((sf[3][r] - mn) * KSC);
      sm_l[r] = sm_l[r] * exp2f((m_l[r] - mn) * KSC) + ps;
      m_l[r] = mn;
    }
  }

  // merge stats across the 16-lane row group
  float m_f[4], rs[4];
#pragma unroll
  for (int r = 0; r < 4; ++r) {
    float mm = m_l[r], ss = sm_l[r];
#pragma unroll
    for (int d = 1; d < 16; d <<= 1) {
      const float om = __shfl_xor(mm, d);
      const float os = __shfl_xor(ss, d);
      const float M2 = fmaxf(mm, om);
      ss = ss * exp2f((mm - M2) * KSC) + os * exp2f((om - M2) * KSC);
      mm = M2;
    }
    m_f[r] = mm;
    rs[r] = 1.0f / ss;
  }

  // ================= sweep 2: probs + AV =================
  const int vd = tid >> 3, vseg = tid & 7;   // V staging assignment
  f32x4 of0 = zf, of1 = zf;
  for (int t = 0; t < 16; ++t) {
    const int j0 = t * 64;
    const int r0 = i0 - j0 + 960;

    // V tile global->regs (issued early; anchored by the ds_write after [A])
    const bf16x8 vgh = *(const bf16x8*)&vth[(size_t)vd * TSEQ + j0 + vseg * 8];
    const bf16x8 vgl = *(const bf16x8*)&vtl[(size_t)vd * TSEQ + j0 + vseg * 8];

    f32x4 mf[8];
#pragma unroll
    for (int st = 0; st < 8; ++st) mf[st] = zf;
#pragma unroll
    for (int st = 0; st < 8; ++st) {
      int pr = r0 + 16 * st + lc;
      if (pr > 2046) pr = 2046;
      const size_t o = (size_t)pr * DHEAD + 8 * lg;
      const bf16x8 bh8 = *(const bf16x8*)&ph_[o];
      const bf16x8 bl8 = *(const bf16x8*)&pl_[o];
      mf[st] = MFMA16(qvh, bh8, mf[st], 0, 0, 0);
      mf[st] = MFMA16(qvl, bh8, mf[st], 0, 0, 0);
      mf[st] = MFMA16(qvh, bl8, mf[st], 0, 0, 0);
    }
    __syncthreads();                     // [A] prev tile's Pt/VT reads done
#pragma unroll
    for (int st = 0; st < 8; ++st)
#pragma unroll
      for (int r = 0; r < 4; ++r)
        Mlds[(16 * w + 4 * lg + r) * 132 + 16 * st + lc] = mf[st][r];
    *(bf16x8*)&VTh[vd * 72 + vseg * 8] = vgh;
    *(bf16x8*)&VTl[vd * 72 + vseg * 8] = vgl;

    f32x4 sf[4];
#pragma unroll
    for (int st = 0; st < 4; ++st) sf[st] = zf;
#pragma unroll
    for (int st = 0; st < 4; ++st) {
      const size_t o = (size_t)(j0 + 16 * st + lc) * DHEAD + 8 * lg;
      const bf16x8 bh8 = *(const bf16x8*)&kh[o];
      const bf16x8 bl8 = *(const bf16x8*)&kl[o];
      sf[st] = MFMA16(quh, bh8, sf[st], 0, 0, 0);
      sf[st] = MFMA16(qul, bh8, sf[st], 0, 0, 0);
      sf[st] = MFMA16(quh, bl8, sf[st], 0, 0, 0);
    }
    __syncthreads();                     // [B] Mlds + VT visible

    float preg[4][4];
#pragma unroll
    for (int st = 0; st < 4; ++st) {
      const int jloc = 16 * st + lc;
#pragma unroll
      for (int r = 0; r < 4; ++r) {
        const int il = 16 * w + 4 * lg + r;
        const float sv = sf[st][r] + Mlds[il * 132 + (il - jloc + 63)];
        preg[st][r] = exp2f((sv - m_f[r]) * KSC) * rs[r];
      }
    }
    __syncthreads();                     // [D] all Mlds gather reads done
#pragma unroll
    for (int st = 0; st < 4; ++st)
#pragma unroll
      for (int r = 0; r < 4; ++r)
        Pt[(16 * w + 4 * lg + r) * 68 + 16 * st + lc] = preg[st][r];
    __syncthreads();                     // [C] probs tile complete
    // global attn store (256B runs per row quarter)
    {
      const int prow = tid >> 2, cb = (tid & 3) * 16;
      float* gp = &arow[(size_t)(i0 + prow) * TSEQ + j0 + cb];
      const float* sp = &Pt[prow * 68 + cb];
#pragma unroll
      for (int qq = 0; qq < 4; ++qq)
        *(float4*)&gp[qq * 4] = *(const float4*)&sp[qq * 4];
    }
    // AV: O[16x32] += probs(16x64) x V(64x32); V from LDS (pre-split bf16)
#pragma unroll
    for (int kc = 0; kc < 2; ++kc) {
      float tmp[8];
      const float* ap = &Pt[(16 * w + lc) * 68 + 32 * kc + 8 * lg];
      *(float4*)&tmp[0] = *(const float4*)&ap[0];
      *(float4*)&tmp[4] = *(const float4*)&ap[4];
      bf16x8 pah, pal;
      cvt8(tmp, pah, pal);
      const bf16x8 b0h = *(const bf16x8*)&VTh[lc * 72 + kc * 32 + 8 * lg];
      const bf16x8 b0l = *(const bf16x8*)&VTl[lc * 72 + kc * 32 + 8 * lg];
      const bf16x8 b1h = *(const bf16x8*)&VTh[(lc + 16) * 72 + kc * 32 + 8 * lg];
      const bf16x8 b1l = *(const bf16x8*)&VTl[(lc + 16) * 72 + kc * 32 + 8 * lg];
      of0 = MFMA16(pah, b0h, of0, 0, 0, 0);
      of0 = MFMA16(pal, b0h, of0, 0, 0, 0);
      of0 = MFMA16(pah, b0l, of0, 0, 0, 0);
      of1 = MFMA16(pah, b1h, of1, 0, 0, 0);
      of1 = MFMA16(pal, b1h, of1, 0, 0, 0);
      of1 = MFMA16(pah, b1l, of1, 0, 0, 0);
    }
  }

  // write O head slice pre-split for MFMA oproj
#pragma unroll
  for (int r = 0; r < 4; ++r) {
    const int row = i0 + 16 * w + 4 * lg + r;
    const size_t base = ((size_t)bb * TSEQ + row) * DMODEL + h * DHEAD;
    unsigned short a2, b2;
    split2(of0[r], a2, b2); obhi[base + lc]      = a2; oblo[base + lc]      = b2;
    split2(of1[r], a2, b2); obhi[base + lc + 16] = a2; oblo[base + lc + 16] = b2;
  }
}

// ---------------------------------------------------------------------------
// MFMA output projection: obuf-split x Wo-split + bo -> out0 fp32.
__global__ __launch_bounds__(256) void oproj_mfma(
    const unsigned short* __restrict__ obhi, const unsigned short* __restrict__ oblo,
    const unsigned short* __restrict__ woh,
    const float* __restrict__ bo, float* __restrict__ out)
{
  const unsigned short* wol = woh + 65536;
  const int c0  = blockIdx.y * 128;
  const int bt0 = blockIdx.x * 64;
  const int tid = threadIdx.x;
  const int w = tid >> 6, lane = tid & 63, lc = lane & 15, lg = lane >> 4;

  const int arow = bt0 + 16 * w + lc;
  bf16x8 ah[8], al[8];
#pragma unroll
  for (int ks = 0; ks < 8; ++ks) {
    const size_t o = (size_t)arow * 256 + ks * 32 + 8 * lg;
    ah[ks] = *(const bf16x8*)&obhi[o];
    al[ks] = *(const bf16x8*)&oblo[o];
  }
  const f32x4 zf = {0.f, 0.f, 0.f, 0.f};
  for (int ct = 0; ct < 8; ++ct) {
    const int n = c0 + ct * 16 + lc;
    f32x4 acc = zf;
#pragma unroll
    for (int ks = 0; ks < 8; ++ks) {
      const size_t o = (size_t)n * 256 + ks * 32 + 8 * lg;
      const bf16x8 bh8 = *(const bf16x8*)&woh[o];
      const bf16x8 bl8 = *(const bf16x8*)&wol[o];
      acc = MFMA16(ah[ks], bh8, acc, 0, 0, 0);
      acc = MFMA16(al[ks], bh8, acc, 0, 0, 0);
      acc = MFMA16(ah[ks], bl8, acc, 0, 0, 0);
    }
    const float bz = bo[n];
#pragma unroll
    for (int r = 0; r < 4; ++r) {
      const int bt = bt0 + 16 * w + 4 * lg + r;
      out[(size_t)bt * DMODEL + n] = acc[r] + bz;
    }
  }
}

// ---------------------------------------------------------------------------
extern "C" void kernel_launch(void* const* d_in, const int* in_sizes, int n_in,
                              void* d_out, int out_size, void* d_ws, size_t ws_size,
                              hipStream_t stream) {
  const float* X   = (const float*)d_in[0];
  const float* Wq  = (const float*)d_in[1];
  const float* bq  = (const float*)d_in[2];
  const float* Wk  = (const float*)d_in[3];
  const float* bk  = (const float*)d_in[4];
  const float* Wv  = (const float*)d_in[5];
  const float* bv  = (const float*)d_in[6];
  const float* Wp  = (const float*)d_in[7];
  const float* Wo  = (const float*)d_in[8];
  const float* bo  = (const float*)d_in[9];
  const float* ub  = (const float*)d_in[10];
  const float* vbb = (const float*)d_in[11];

  float* ws = (float*)d_ws;
  float* qbuf = ws;                                          // fp32 Q
  unsigned short* khi  = (unsigned short*)(ws + 2097152u);
  unsigned short* klo  = khi + 2097152u;
  unsigned short* pehi = khi;            // alias: pe table dead before K write
  unsigned short* pelo = pehi + 524032u;
  unsigned short* vthi = (unsigned short*)(ws + 4194304u);
  unsigned short* vtlo = vthi + 2097152u;
  unsigned short* phi  = (unsigned short*)(ws + 6291456u);
  unsigned short* plo  = phi + 524032u;
  unsigned short* obhi = (unsigned short*)(ws + 6815488u);   // O region
  unsigned short* oblo = obhi + 2097152u;
  unsigned short* xhi  = obhi;   // alias: X-split dead before attn writes obuf
  unsigned short* xlo  = oblo;
  unsigned short* wsp  = (unsigned short*)(ws + 8912640u);   // 5x(hi+lo) W split

  float* out0 = (float*)d_out;
  float* attn = out0 + OUT0;

  prep_kernel<<<4415, 256, 0, stream>>>(X, Wq, Wk, Wv, Wp, Wo, xhi, xlo, wsp,
                                        pehi, pelo);
  pgemm_mfma<<<dim3(32, 2), 256, 0, stream>>>(pehi, pelo, wsp + 3 * 131072,
                                              phi, plo);
  proj_qkv_mfma<<<dim3(128, 6), 256, 0, stream>>>(xhi, xlo, wsp, bq, bk, bv,
                                                  qbuf, khi, klo, vthi, vtlo);
  attn_kernel<<<1024, 256, 0, stream>>>(qbuf, khi, klo, vthi, vtlo, phi, plo,
                                        ub, vbb, attn, obhi, oblo);
  oproj_mfma<<<dim3(128, 2), 256, 0, stream>>>(obhi, oblo, wsp + 4 * 131072,
                                               bo, out0);
}